// Round 6
// baseline (946.471 us; speedup 1.0000x reference)
//
#include <hip/hip_runtime.h>
#include <cstdint>
#include <cstddef>

// Problem constants
#define B_    64
#define N_    64
#define D_    2048
#define NB_   8
#define W_    57           // N - NB + 1
#define QKVLD 6144         // q|k|v concatenated row stride (gemm1 output)
#define QKLD  4096         // q2|k2 row stride (gemm2 output)
#define SCALE_ 0.022097086912079612f  // 1/sqrt(2048)

// ---------- helpers ----------
__device__ __forceinline__ float bf2f(unsigned short u){
  union { unsigned int i; float f; } x; x.i = ((unsigned int)u) << 16; return x.f;
}
__device__ __forceinline__ unsigned short f2bf(float f){
  union { float f; unsigned int i; } x; x.f = f;
  unsigned int r = x.i + 0x7fffu + ((x.i >> 16) & 1u);
  return (unsigned short)(r >> 16);
}

// ---------- fused cast: fc + nsa wq/wk/wv + both bias concats ----------
__global__ __launch_bounds__(256) void castA(const float* __restrict__ fc,
                                             const float* __restrict__ wq,
                                             const float* __restrict__ wk,
                                             const float* __restrict__ wv,
                                             const float* __restrict__ nq,
                                             const float* __restrict__ nk,
                                             const float* __restrict__ nv,
                                             const float* __restrict__ sq,
                                             const float* __restrict__ sk,
                                             unsigned short* __restrict__ fc16,
                                             unsigned short* __restrict__ wcat,
                                             float* __restrict__ b1,
                                             float* __restrict__ b2){
  const int i = blockIdx.x * 256 + threadIdx.x;   // [0, 5249024)
  if (i >= 5242880) {                             // bias tail: 6144 elems
    const int k = i - 5242880;
    const int sel = k >> 11, off = k & 2047;
    b1[k] = (sel == 0) ? nq[off] : (sel == 1) ? nk[off] : nv[off];
    if (sel < 2) b2[k] = (sel == 0) ? sq[off] : sk[off];
    return;
  }
  float4 v; ushort4* dst;
  if (i < 2097152) {
    v = ((const float4*)fc)[i];
    dst = (ushort4*)fc16 + i;
  } else {
    const int j = i - 2097152;
    const int sel = j >> 20;
    const float* s = (sel == 0) ? wq : (sel == 1) ? wk : wv;
    v = ((const float4*)s)[j & 1048575];
    dst = (ushort4*)wcat + j;
  }
  ushort4 o; o.x = f2bf(v.x); o.y = f2bf(v.y); o.z = f2bf(v.z); o.w = f2bf(v.w);
  *dst = o;
}

// ---------- cast sa weights: swq,swk -> wcat2 (contiguous), swv -> swv16 ----------
__global__ __launch_bounds__(256) void castB3(const float* __restrict__ a,
                                              const float* __restrict__ b,
                                              const float* __restrict__ c,
                                              unsigned short* __restrict__ wcat2,
                                              unsigned short* __restrict__ swv16){
  const int i = blockIdx.x * 256 + threadIdx.x;   // [0, 3145728)
  const int sel = i >> 20;
  const int j = i & 1048575;
  const float* s = (sel == 0) ? a : (sel == 1) ? b : c;
  const float4 v = ((const float4*)s)[j];
  ushort4 o; o.x = f2bf(v.x); o.y = f2bf(v.y); o.z = f2bf(v.z); o.w = f2bf(v.w);
  if (sel < 2) ((ushort4*)wcat2)[i] = o;
  else         ((ushort4*)swv16)[j] = o;
}

// ---------- bf16 GEMM: C[M][N] = A[M][K] @ B[N][K]^T + bias[N]  (m97 recipe) ----------
typedef __attribute__((ext_vector_type(8))) short bfrag8;   // 8 bf16 = 4 VGPR
typedef __attribute__((ext_vector_type(4))) float facc4;    // 4 fp32 acc

__global__ __launch_bounds__(256, 3) void gemm_bt(
    const unsigned short* __restrict__ A,
    const unsigned short* __restrict__ Bw,
    const float* __restrict__ bias,
    unsigned short* __restrict__ C,
    int N, int K, int perx)
{
  __shared__ __align__(16) unsigned short lA[128 * 32];
  __shared__ __align__(16) unsigned short lB[128 * 32];
  const int flat = blockIdx.x;
  const int xcd = flat & 7;
  const int idx = flat >> 3;
  const int ct = xcd + 8 * (idx % perx);
  const int rt = idx / perx;
  const int t = threadIdx.x;
  const int lane = t & 63, wid = t >> 6;
  const int wm = wid >> 1, wn = wid & 1;
  const size_t rowBase = (size_t)rt * 128;
  const size_t colBase = (size_t)ct * 128;
  const int sr = lane >> 2, sg = lane & 3;     // staging: 4 lanes/row, 16B each

  const unsigned short* gA0 = A  + (rowBase + (size_t)(wid * 16 + sr)) * K + sg * 8;
  const unsigned short* gB0 = Bw + (colBase + (size_t)(wid * 16 + sr)) * K + sg * 8;
  unsigned short* lA0 = &lA[(wid * 16) * 32];  // wave-uniform LDS base
  unsigned short* lB0 = &lB[(wid * 16) * 32];

  facc4 acc[4][4];
  #pragma unroll
  for (int i = 0; i < 4; i++)
    #pragma unroll
    for (int j = 0; j < 4; j++) acc[i][j] = 0;

  const int fm = lane & 15, quad = lane >> 4;
  const unsigned short* aAddr = &lA[(wm * 64 + fm) * 32 + quad * 8];
  const unsigned short* bAddr = &lB[(wn * 64 + fm) * 32 + quad * 8];

#define STAGE(k0) do { \
    __builtin_amdgcn_global_load_lds((const __attribute__((address_space(1))) void*)(gA0 + (k0)),                 (__attribute__((address_space(3))) void*)(lA0),            16, 0, 0); \
    __builtin_amdgcn_global_load_lds((const __attribute__((address_space(1))) void*)(gA0 + (size_t)64*K + (k0)),  (__attribute__((address_space(3))) void*)(lA0 + 64*32),    16, 0, 0); \
    __builtin_amdgcn_global_load_lds((const __attribute__((address_space(1))) void*)(gB0 + (k0)),                 (__attribute__((address_space(3))) void*)(lB0),            16, 0, 0); \
    __builtin_amdgcn_global_load_lds((const __attribute__((address_space(1))) void*)(gB0 + (size_t)64*K + (k0)),  (__attribute__((address_space(3))) void*)(lB0 + 64*32),    16, 0, 0); \
  } while (0)

  STAGE(0);
  __syncthreads();
  for (int kt = 0;;) {
    bfrag8 af[4], bf[4];
    #pragma unroll
    for (int i = 0; i < 4; i++) {
      af[i] = *(const bfrag8*)(aAddr + i * 16 * 32);
      bf[i] = *(const bfrag8*)(bAddr + i * 16 * 32);
    }
    #pragma unroll
    for (int i = 0; i < 4; i++)
      #pragma unroll
      for (int j = 0; j < 4; j++)
        acc[i][j] = __builtin_amdgcn_mfma_f32_16x16x32_bf16(af[i], bf[j], acc[i][j], 0, 0, 0);
    kt += 32;
    if (kt >= K) break;
    __syncthreads();
    STAGE(kt);
    __syncthreads();
  }
#undef STAGE

  // epilogue: D row = quad*4+rr, col = lane&15 (m89/m91-verified layout)
  #pragma unroll
  for (int i = 0; i < 4; i++) {
    const size_t r0 = rowBase + wm * 64 + i * 16 + quad * 4;
    #pragma unroll
    for (int j = 0; j < 4; j++) {
      const size_t cc = colBase + wn * 64 + j * 16 + fm;
      const float bv = bias[cc];
      #pragma unroll
      for (int rr = 0; rr < 4; rr++)
        C[(r0 + rr) * (size_t)N + cc] = f2bf(acc[i][j][rr] + bv);
    }
  }
}

// ---------- MFMA scores with K-split: Spart[b][ks][64][64] = q_chunk @ k_chunk^T ----------
__global__ __launch_bounds__(256) void scores_kernel(
    const unsigned short* __restrict__ qkv, int rowsPerBatch, int ld,
    float* __restrict__ Spart)
{
  __shared__ __align__(16) unsigned short lq[64 * 32];
  __shared__ __align__(16) unsigned short lk[64 * 32];
  const int b = blockIdx.x, ks = blockIdx.y;
  const int t = threadIdx.x, lane = t & 63, wid = t >> 6;
  const int sr = lane >> 2, sg = lane & 3;
  const unsigned short* gq = qkv + ((size_t)b * rowsPerBatch + wid * 16 + sr) * ld
                             + ks * 256 + sg * 8;
  const unsigned short* gk = gq + 2048;
  unsigned short* lq0 = &lq[(wid * 16) * 32];
  unsigned short* lk0 = &lk[(wid * 16) * 32];
  const int fm = lane & 15, quad = lane >> 4;
  const unsigned short* aAddr = &lq[(wid * 16 + fm) * 32 + quad * 8];

  facc4 acc[4];
  #pragma unroll
  for (int j = 0; j < 4; j++) acc[j] = 0;

#define STAGE2(k0) do { \
    __builtin_amdgcn_global_load_lds((const __attribute__((address_space(1))) void*)(gq + (k0)), (__attribute__((address_space(3))) void*)(lq0), 16, 0, 0); \
    __builtin_amdgcn_global_load_lds((const __attribute__((address_space(1))) void*)(gk + (k0)), (__attribute__((address_space(3))) void*)(lk0), 16, 0, 0); \
  } while (0)

  STAGE2(0);
  __syncthreads();
  for (int kk = 0;;) {
    const bfrag8 af = *(const bfrag8*)aAddr;
    #pragma unroll
    for (int j = 0; j < 4; j++) {
      const bfrag8 bf = *(const bfrag8*)(&lk[(j * 16 + fm) * 32 + quad * 8]);
      acc[j] = __builtin_amdgcn_mfma_f32_16x16x32_bf16(af, bf, acc[j], 0, 0, 0);
    }
    kk += 32;
    if (kk >= 256) break;
    __syncthreads();
    STAGE2(kk);
    __syncthreads();
  }
#undef STAGE2

  float* sp = Spart + (size_t)(b * 8 + ks) * 4096;
  const int r0 = wid * 16 + quad * 4;
  #pragma unroll
  for (int j = 0; j < 4; j++)
    #pragma unroll
    for (int rr = 0; rr < 4; rr++)
      sp[(r0 + rr) * 64 + j * 16 + fm] = acc[j][rr];
}

// ---------- out-projection partials: Opart[ks][64 b][2048 d] = y16 @ swv16^T (K-chunk) ----------
__global__ __launch_bounds__(256) void outproj(
    const unsigned short* __restrict__ y16, const unsigned short* __restrict__ swv16,
    float* __restrict__ Opart)
{
  __shared__ __align__(16) unsigned short ly[64 * 32];
  __shared__ __align__(16) unsigned short lv[64 * 32];
  const int dt = blockIdx.x, ks = blockIdx.y;     // 32 d-tiles x 8 k-splits
  const int t = threadIdx.x, lane = t & 63, wid = t >> 6;
  const int sr = lane >> 2, sg = lane & 3;
  const unsigned short* gy = y16  + (size_t)(wid * 16 + sr) * 2048 + ks * 256 + sg * 8;
  const unsigned short* gv = swv16 + (size_t)(dt * 64 + wid * 16 + sr) * 2048 + ks * 256 + sg * 8;
  unsigned short* ly0 = &ly[(wid * 16) * 32];
  unsigned short* lv0 = &lv[(wid * 16) * 32];
  const int fm = lane & 15, quad = lane >> 4;
  const unsigned short* aAddr = &ly[(wid * 16 + fm) * 32 + quad * 8];

  facc4 acc[4];
  #pragma unroll
  for (int j = 0; j < 4; j++) acc[j] = 0;

#define STAGE3(k0) do { \
    __builtin_amdgcn_global_load_lds((const __attribute__((address_space(1))) void*)(gy + (k0)), (__attribute__((address_space(3))) void*)(ly0), 16, 0, 0); \
    __builtin_amdgcn_global_load_lds((const __attribute__((address_space(1))) void*)(gv + (k0)), (__attribute__((address_space(3))) void*)(lv0), 16, 0, 0); \
  } while (0)

  STAGE3(0);
  __syncthreads();
  for (int kk = 0;;) {
    const bfrag8 af = *(const bfrag8*)aAddr;
    #pragma unroll
    for (int j = 0; j < 4; j++) {
      const bfrag8 bf = *(const bfrag8*)(&lv[(j * 16 + fm) * 32 + quad * 8]);
      acc[j] = __builtin_amdgcn_mfma_f32_16x16x32_bf16(af, bf, acc[j], 0, 0, 0);
    }
    kk += 32;
    if (kk >= 256) break;
    __syncthreads();
    STAGE3(kk);
    __syncthreads();
  }
#undef STAGE3

  float* op = Opart + (size_t)ks * 131072 + (size_t)dt * 64;
  const int r0 = wid * 16 + quad * 4;   // b row
  #pragma unroll
  for (int j = 0; j < 4; j++)
    #pragma unroll
    for (int rr = 0; rr < 4; rr++)
      op[(size_t)(r0 + rr) * 2048 + j * 16 + fm] = acc[j][rr];
}

// ---------- out[b][d] = sum_ks Opart + sumc2[b]*sbv[d] ----------
__global__ __launch_bounds__(256) void outfin(const float* __restrict__ Opart,
                                              const float* __restrict__ c2buf,
                                              const float* __restrict__ sbv,
                                              float* __restrict__ out){
  const int i = blockIdx.x * 256 + threadIdx.x;   // [0, 131072)
  const int b = i >> 11, d = i & 2047;
  float s = 0.f;
  #pragma unroll
  for (int ks = 0; ks < 8; ks++) s += Opart[(size_t)ks * 131072 + i];
  out[i] = s + c2buf[(size_t)b * 64 + 63] * sbv[d];
}

// ---------- NSA finisher: reduce partials + band softmax column-sums ----------
__global__ __launch_bounds__(512) void nsa_fin(const float* __restrict__ Spart,
                                               float* __restrict__ cbuf){
  __shared__ float Ss[64][65];
  const int b = blockIdx.x, t = threadIdx.x;
  const float* sp = Spart + (size_t)b * 8 * 4096;
  for (int idx = t; idx < 4096; idx += 512) {
    float s = 0.f;
    #pragma unroll
    for (int ks = 0; ks < 8; ks++) s += sp[ks * 4096 + idx];
    Ss[idx >> 6][idx & 63] = s * SCALE_;
  }
  __syncthreads();
  if (t < W_ * 8) {
    const int wi = t >> 3, jp = t & 7;
    float csum = 0.f;
    for (int ip = 0; ip < 8; ip++) {
      const float* row = &Ss[wi + ip][wi];
      float mx = row[0];
      #pragma unroll
      for (int q = 1; q < 8; q++) mx = fmaxf(mx, row[q]);
      float s = 0.f, ej = 0.f;
      #pragma unroll
      for (int q = 0; q < 8; q++) { float e = __expf(row[q] - mx); s += e; if (q == jp) ej = e; }
      csum += ej / s;
    }
    cbuf[((size_t)b * W_ + wi) * 8 + jp] = csum;
  }
}

// ---------- SA2 finisher: reduce partials + softmax column-sums c2[b][j], sumc at slot 63 ----------
__global__ __launch_bounds__(512) void sa2_c2(const float* __restrict__ Spart,
                                              float* __restrict__ c2buf){
  __shared__ float Ss[64][65];
  __shared__ float rowm[64], rowsum[64], c2s[64];
  const int b = blockIdx.x, t = threadIdx.x;
  const float* sp = Spart + (size_t)b * 8 * 4096;
  for (int idx = t; idx < 4096; idx += 512) {
    float s = 0.f;
    #pragma unroll
    for (int ks = 0; ks < 8; ks++) s += sp[ks * 4096 + idx];
    Ss[idx >> 6][idx & 63] = s * SCALE_;
  }
  __syncthreads();
  if (t < W_) {
    float mx = -1e30f;
    for (int j = 0; j < W_; j++) mx = fmaxf(mx, Ss[t][j]);
    float s = 0.f;
    for (int j = 0; j < W_; j++) s += __expf(Ss[t][j] - mx);
    rowm[t] = mx; rowsum[t] = 1.f / s;
  }
  __syncthreads();
  if (t < W_) {
    float cs = 0.f;
    for (int i = 0; i < W_; i++) cs += __expf(Ss[i][t] - rowm[i]) * rowsum[i];
    c2s[t] = cs;
    c2buf[(size_t)b * 64 + t] = cs;
  }
  __syncthreads();
  if (t == 0) {
    float s = 0.f;
    for (int j = 0; j < W_; j++) s += c2s[j];
    c2buf[(size_t)b * 64 + 63] = s;
  }
}

// ---------- y16[b][d] = bf16( sum_j c2[b][j] * hn[b*57+j][d] ) ----------
__global__ __launch_bounds__(256) void ycomb(const unsigned short* __restrict__ hn,
                                             const float* __restrict__ c2buf,
                                             unsigned short* __restrict__ y16){
  const int b = blockIdx.y;
  const int d = blockIdx.x * 256 + threadIdx.x;
  __shared__ float c2[W_];
  if (threadIdx.x < W_) c2[threadIdx.x] = c2buf[(size_t)b * 64 + threadIdx.x];
  __syncthreads();
  const unsigned short* hrow = hn + (size_t)b * W_ * 2048 + d;
  float a = 0.f;
  for (int j = 0; j < W_; j++) a += c2[j] * bf2f(hrow[(size_t)j * 2048]);
  y16[(size_t)b * 2048 + d] = f2bf(a);
}

// ---------- fused h + LayerNorm: hn[b*57+w][:] = LN(ds-proj + nsa), bf16 ----------
// grid 520 (1D): flat<512 -> wg=flat>>6 (8 w-rows each, last group 1), b=flat&63
//                flat>=512 -> zero pad rows [3648,3712)
typedef __attribute__((ext_vector_type(8))) unsigned short us8;
__global__ __launch_bounds__(256) void hln_kernel(
    const unsigned short* __restrict__ fc16, const float* __restrict__ dsw,
    const float* __restrict__ dsb, const unsigned short* __restrict__ qkv,
    const float* __restrict__ cbuf, const float* __restrict__ g,
    const float* __restrict__ be, unsigned short* __restrict__ hn)
{
  const int flat = blockIdx.x;
  const int t = threadIdx.x;
  if (flat >= 512) {
    const int p = flat - 512;                      // 8 blocks, 8 rows each
    unsigned short* orow = hn + (size_t)(3648 + p * 8) * 2048;
    for (int i = t; i < 8 * 2048; i += 256) orow[i] = 0;
    return;
  }
  const int wg = flat >> 6, b = flat & 63;
  const int w0 = wg * 8;
  const int nw = (wg == 7) ? 1 : 8;                // 57 = 7*8 + 1
  __shared__ float dswl[8 * 64];
  __shared__ float cl[8 * 8];
  __shared__ float dsbl[8];
  __shared__ float red[4][8][2];
  for (int i = t; i < nw * 64; i += 256) dswl[i] = dsw[(w0 + (i >> 6)) * 64 + (i & 63)];
  for (int i = t; i < nw * 8; i += 256) cl[i] = cbuf[((size_t)b * W_ + w0 + (i >> 3)) * 8 + (i & 7)];
  if (t < nw) dsbl[t] = dsb[w0 + t];
  __syncthreads();

  const int d0 = t * 8;                            // this thread's 8 contiguous d
  float acc[8][8];
  #pragma unroll
  for (int w = 0; w < 8; w++)
    #pragma unroll
    for (int p = 0; p < 8; p++) acc[w][p] = 0.f;

  // ds-GEMM: acc[w][p] += fc[b][n][d0+p] * dsw[w0+w][n]
  for (int n = 0; n < 64; n++) {
    const us8 fv8 = *(const us8*)(fc16 + ((size_t)b * 64 + n) * 2048 + d0);
    float fv[8];
    #pragma unroll
    for (int p = 0; p < 8; p++) fv[p] = bf2f(fv8[p]);
    for (int w = 0; w < nw; w++) {
      const float dv = dswl[w * 64 + n];
      #pragma unroll
      for (int p = 0; p < 8; p++) acc[w][p] += fv[p] * dv;
    }
  }
  // nsa combine: rows w0..w0+nw+6 of v
  for (int r = 0; r < nw + 7; r++) {
    const us8 vv8 = *(const us8*)(qkv + ((size_t)b * 64 + w0 + r) * QKVLD + 4096 + d0);
    float vv[8];
    #pragma unroll
    for (int p = 0; p < 8; p++) vv[p] = bf2f(vv8[p]);
    #pragma unroll
    for (int j = 0; j < 8; j++) {
      const int w = r - j;
      if (w >= 0 && w < nw) {
        const float cv = cl[w * 8 + j];
        #pragma unroll
        for (int p = 0; p < 8; p++) acc[w][p] += cv * vv[p];
      }
    }
  }
  // add bias, accumulate row sums
  float s1[8], s2v[8];
  for (int w = 0; w < nw; w++) {
    const float bb = dsbl[w];
    float a1 = 0.f, a2 = 0.f;
    #pragma unroll
    for (int p = 0; p < 8; p++) {
      acc[w][p] += bb;
      a1 += acc[w][p];
      a2 += acc[w][p] * acc[w][p];
    }
    s1[w] = a1; s2v[w] = a2;
  }
  // wave reduce then LDS combine (single sync)
  const int wv = t >> 6, lane = t & 63;
  for (int w = 0; w < nw; w++) {
    #pragma unroll
    for (int off = 32; off >= 1; off >>= 1) {
      s1[w]  += __shfl_down(s1[w], off);
      s2v[w] += __shfl_down(s2v[w], off);
    }
    if (lane == 0) { red[wv][w][0] = s1[w]; red[wv][w][1] = s2v[w]; }
  }
  __syncthreads();
  // load ln params for this thread's d
  const float4 g0 = *(const float4*)(g + d0),  g1 = *(const float4*)(g + d0 + 4);
  const float4 e0 = *(const float4*)(be + d0), e1 = *(const float4*)(be + d0 + 4);
  const float gp[8] = {g0.x,g0.y,g0.z,g0.w,g1.x,g1.y,g1.z,g1.w};
  const float ep[8] = {e0.x,e0.y,e0.z,e0.w,e1.x,e1.y,e1.z,e1.w};
  for (int w = 0; w < nw; w++) {
    const float st  = red[0][w][0] + red[1][w][0] + red[2][w][0] + red[3][w][0];
    const float st2 = red[0][w][1] + red[1][w][1] + red[2][w][1] + red[3][w][1];
    const float mu  = st * (1.f / 2048.f);
    const float var = st2 * (1.f / 2048.f) - mu * mu;
    const float rstd = rsqrtf(var + 1e-5f);
    us8 o;
    #pragma unroll
    for (int p = 0; p < 8; p++)
      o[p] = f2bf((acc[w][p] - mu) * rstd * gp[p] + ep[p]);
    *(us8*)(hn + (size_t)(b * W_ + w0 + w) * 2048 + d0) = o;
  }
}

// ---------- launch ----------
extern "C" void kernel_launch(void* const* d_in, const int* in_sizes, int n_in,
                              void* d_out, int out_size, void* d_ws, size_t ws_size,
                              hipStream_t stream)
{
  const float* fc  = (const float*)d_in[0];
  const float* nwq = (const float*)d_in[1];
  const float* nbq = (const float*)d_in[2];
  const float* nwk = (const float*)d_in[3];
  const float* nbk = (const float*)d_in[4];
  const float* nwv = (const float*)d_in[5];
  const float* nbv = (const float*)d_in[6];
  const float* dsw = (const float*)d_in[7];
  const float* dsb = (const float*)d_in[8];
  const float* lng = (const float*)d_in[9];
  const float* lnb = (const float*)d_in[10];
  const float* swq = (const float*)d_in[11];
  const float* sbq = (const float*)d_in[12];
  const float* swk = (const float*)d_in[13];
  const float* sbk = (const float*)d_in[14];
  const float* swv = (const float*)d_in[15];
  const float* sbv = (const float*)d_in[16];
  (void)sbk;

  char* ws = (char*)d_ws;
  unsigned short* fc16  = (unsigned short*)(ws + 0);          // 16.8 MB
  unsigned short* wcat  = (unsigned short*)(ws + 16777216);   // 25.2 MB (nsa weights; dead after gemm1)
  float* Spart          = (float*)(ws + 16777216);            // 8.4 MB — aliases wcat head
  unsigned short* wcat2 = (unsigned short*)(ws + 25165824);   // 16.8 MB ([swq;swk]; dead after gemm2)
  float* bcat1          = (float*)(ws + 41943040);            // 24 KB
  float* bcat2          = (float*)(ws + 41967616);            // 16 KB used
  unsigned short* qkv   = (unsigned short*)(ws + 41992192);   // 50.3 MB (phase2: q2|k2 30.4 MB)
  float* cbuf           = (float*)(ws + 92323840);            // 117 KB (reused: c2buf)
  float* c2buf          = (float*)(ws + 92323840);            // aliases cbuf (disjoint lifetime)
  unsigned short* swv16 = (unsigned short*)(ws + 92440576);   // 8.4 MB
  unsigned short* y16   = (unsigned short*)(ws + 100829184);  // 256 KB
  float* Opart          = (float*)(ws + 101091328);           // 4 MB
  unsigned short* hn    = (unsigned short*)(ws + 122324992);  // 15.2 MB   (total ~137.5 MB)

  // fused casts + bias concats (exact grid: 5249024 / 256 = 20504)
  castA<<<20504, 256, 0, stream>>>(fc, nwq, nwk, nwv, nbq, nbk, nbv, sbq, sbk,
                                   fc16, wcat, bcat1, bcat2);

  // qkv = fc16 @ [wq;wk;wv]^T + bias   (M=4096, N=6144, K=2048), 48 col-tiles, 6/XCD
  gemm_bt<<<32 * 48, 256, 0, stream>>>(fc16, wcat, bcat1, qkv, 6144, 2048, 6);

  // NSA band scores via MFMA, K-split x8 (Spart overwrites nsa weights — gemm1 done)
  scores_kernel<<<dim3(64, 8), 256, 0, stream>>>(qkv, 64, QKVLD, Spart);
  nsa_fin<<<64, 512, 0, stream>>>(Spart, cbuf);

  // fused h + LayerNorm -> hn (bf16; pad rows zeroed by blocks 512..519)
  hln_kernel<<<520, 256, 0, stream>>>(fc16, dsw, dsb, qkv, cbuf, lng, lnb, hn);

  // sa weights: swq,swk -> wcat2, swv -> swv16
  castB3<<<12288, 256, 0, stream>>>(swq, swk, swv, wcat2, swv16);

  // q2|k2 = hn @ [swq;swk]^T + bias  (M=3712 padded, N=4096, K=2048), 32 col-tiles, 4/XCD
  gemm_bt<<<29 * 32, 256, 0, stream>>>(hn, wcat2, bcat2, qkv, 4096, 2048, 4);

  // SA2 scores via MFMA (rows b*57..b*57+63; max 3654 < 3712, in-bounds)
  scores_kernel<<<dim3(64, 8), 256, 0, stream>>>(qkv, W_, QKLD, Spart);
  sa2_c2<<<64, 512, 0, stream>>>(Spart, c2buf);

  // y16 = bf16(c2^T · hn); out = y16 @ swv16^T (MFMA, K-split x8) + sumc*sbv
  ycomb<<<dim3(8, 64), 256, 0, stream>>>(hn, c2buf, y16);
  outproj<<<dim3(32, 8), 256, 0, stream>>>(y16, swv16, Opart);
  outfin<<<512, 256, 0, stream>>>(Opart, c2buf, sbv, (float*)d_out);

  (void)in_sizes; (void)n_in; (void)out_size; (void)ws_size;
}

// Round 7
// 441.880 us; speedup vs baseline: 2.1419x; 2.1419x over previous
//
#include <hip/hip_runtime.h>
#include <cstdint>
#include <cstddef>

// Problem constants
#define B_    64
#define N_    64
#define D_    2048
#define NB_   8
#define W_    57           // N - NB + 1
#define QKVLD 6144         // q|k|v concatenated row stride (gemm1 output)
#define QKLD  4096         // q2|k2 row stride (gemm2 output)
#define SCALE_ 0.022097086912079612f  // 1/sqrt(2048)

// ---------- helpers ----------
__device__ __forceinline__ float bf2f(unsigned short u){
  union { unsigned int i; float f; } x; x.i = ((unsigned int)u) << 16; return x.f;
}
__device__ __forceinline__ unsigned short f2bf(float f){
  union { float f; unsigned int i; } x; x.f = f;
  unsigned int r = x.i + 0x7fffu + ((x.i >> 16) & 1u);
  return (unsigned short)(r >> 16);
}

// ---------- fused cast: fc + nsa wq/wk/wv + both bias concats ----------
__global__ __launch_bounds__(256) void castA(const float* __restrict__ fc,
                                             const float* __restrict__ wq,
                                             const float* __restrict__ wk,
                                             const float* __restrict__ wv,
                                             const float* __restrict__ nq,
                                             const float* __restrict__ nk,
                                             const float* __restrict__ nv,
                                             const float* __restrict__ sq,
                                             const float* __restrict__ sk,
                                             unsigned short* __restrict__ fc16,
                                             unsigned short* __restrict__ wcat,
                                             float* __restrict__ b1,
                                             float* __restrict__ b2){
  const int i = blockIdx.x * 256 + threadIdx.x;   // [0, 5249024)
  if (i >= 5242880) {                             // bias tail: 6144 elems
    const int k = i - 5242880;
    const int sel = k >> 11, off = k & 2047;
    b1[k] = (sel == 0) ? nq[off] : (sel == 1) ? nk[off] : nv[off];
    if (sel < 2) b2[k] = (sel == 0) ? sq[off] : sk[off];
    return;
  }
  float4 v; ushort4* dst;
  if (i < 2097152) {
    v = ((const float4*)fc)[i];
    dst = (ushort4*)fc16 + i;
  } else {
    const int j = i - 2097152;
    const int sel = j >> 20;
    const float* s = (sel == 0) ? wq : (sel == 1) ? wk : wv;
    v = ((const float4*)s)[j & 1048575];
    dst = (ushort4*)wcat + j;
  }
  ushort4 o; o.x = f2bf(v.x); o.y = f2bf(v.y); o.z = f2bf(v.z); o.w = f2bf(v.w);
  *dst = o;
}

// ---------- cast sa weights: swq,swk -> wcat2 (contiguous), swv -> swv16 ----------
__global__ __launch_bounds__(256) void castB3(const float* __restrict__ a,
                                              const float* __restrict__ b,
                                              const float* __restrict__ c,
                                              unsigned short* __restrict__ wcat2,
                                              unsigned short* __restrict__ swv16){
  const int i = blockIdx.x * 256 + threadIdx.x;   // [0, 3145728)
  const int sel = i >> 20;
  const int j = i & 1048575;
  const float* s = (sel == 0) ? a : (sel == 1) ? b : c;
  const float4 v = ((const float4*)s)[j];
  ushort4 o; o.x = f2bf(v.x); o.y = f2bf(v.y); o.z = f2bf(v.z); o.w = f2bf(v.w);
  if (sel < 2) ((ushort4*)wcat2)[i] = o;
  else         ((ushort4*)swv16)[j] = o;
}

// ---------- bf16 GEMM: C[M][N] = A[M][K] @ B[N][K]^T + bias[N]  (m97 recipe) ----------
typedef __attribute__((ext_vector_type(8))) short bfrag8;   // 8 bf16 = 4 VGPR
typedef __attribute__((ext_vector_type(4))) float facc4;    // 4 fp32 acc

__global__ __launch_bounds__(256, 3) void gemm_bt(
    const unsigned short* __restrict__ A,
    const unsigned short* __restrict__ Bw,
    const float* __restrict__ bias,
    unsigned short* __restrict__ C,
    int N, int K, int perx)
{
  __shared__ __align__(16) unsigned short lA[128 * 32];
  __shared__ __align__(16) unsigned short lB[128 * 32];
  const int flat = blockIdx.x;
  const int xcd = flat & 7;
  const int idx = flat >> 3;
  const int ct = xcd + 8 * (idx % perx);
  const int rt = idx / perx;
  const int t = threadIdx.x;
  const int lane = t & 63, wid = t >> 6;
  const int wm = wid >> 1, wn = wid & 1;
  const size_t rowBase = (size_t)rt * 128;
  const size_t colBase = (size_t)ct * 128;
  const int sr = lane >> 2, sg = lane & 3;     // staging: 4 lanes/row, 16B each

  const unsigned short* gA0 = A  + (rowBase + (size_t)(wid * 16 + sr)) * K + sg * 8;
  const unsigned short* gB0 = Bw + (colBase + (size_t)(wid * 16 + sr)) * K + sg * 8;
  unsigned short* lA0 = &lA[(wid * 16) * 32];  // wave-uniform LDS base
  unsigned short* lB0 = &lB[(wid * 16) * 32];

  facc4 acc[4][4];
  #pragma unroll
  for (int i = 0; i < 4; i++)
    #pragma unroll
    for (int j = 0; j < 4; j++) acc[i][j] = 0;

  const int fm = lane & 15, quad = lane >> 4;
  const unsigned short* aAddr = &lA[(wm * 64 + fm) * 32 + quad * 8];
  const unsigned short* bAddr = &lB[(wn * 64 + fm) * 32 + quad * 8];

#define STAGE(k0) do { \
    __builtin_amdgcn_global_load_lds((const __attribute__((address_space(1))) void*)(gA0 + (k0)),                 (__attribute__((address_space(3))) void*)(lA0),            16, 0, 0); \
    __builtin_amdgcn_global_load_lds((const __attribute__((address_space(1))) void*)(gA0 + (size_t)64*K + (k0)),  (__attribute__((address_space(3))) void*)(lA0 + 64*32),    16, 0, 0); \
    __builtin_amdgcn_global_load_lds((const __attribute__((address_space(1))) void*)(gB0 + (k0)),                 (__attribute__((address_space(3))) void*)(lB0),            16, 0, 0); \
    __builtin_amdgcn_global_load_lds((const __attribute__((address_space(1))) void*)(gB0 + (size_t)64*K + (k0)),  (__attribute__((address_space(3))) void*)(lB0 + 64*32),    16, 0, 0); \
  } while (0)

  STAGE(0);
  __syncthreads();
  for (int kt = 0;;) {
    bfrag8 af[4], bf[4];
    #pragma unroll
    for (int i = 0; i < 4; i++) {
      af[i] = *(const bfrag8*)(aAddr + i * 16 * 32);
      bf[i] = *(const bfrag8*)(bAddr + i * 16 * 32);
    }
    #pragma unroll
    for (int i = 0; i < 4; i++)
      #pragma unroll
      for (int j = 0; j < 4; j++)
        acc[i][j] = __builtin_amdgcn_mfma_f32_16x16x32_bf16(af[i], bf[j], acc[i][j], 0, 0, 0);
    kt += 32;
    if (kt >= K) break;
    __syncthreads();
    STAGE(kt);
    __syncthreads();
  }
#undef STAGE

  // epilogue: D row = quad*4+rr, col = lane&15 (m89/m91-verified layout)
  #pragma unroll
  for (int i = 0; i < 4; i++) {
    const size_t r0 = rowBase + wm * 64 + i * 16 + quad * 4;
    #pragma unroll
    for (int j = 0; j < 4; j++) {
      const size_t cc = colBase + wn * 64 + j * 16 + fm;
      const float bv = bias[cc];
      #pragma unroll
      for (int rr = 0; rr < 4; rr++)
        C[(r0 + rr) * (size_t)N + cc] = f2bf(acc[i][j][rr] + bv);
    }
  }
}

// ---------- MFMA scores with K-split: Spart[b][ks][64][64] = q_chunk @ k_chunk^T ----------
__global__ __launch_bounds__(256) void scores_kernel(
    const unsigned short* __restrict__ qkv, int rowsPerBatch, int ld,
    float* __restrict__ Spart)
{
  __shared__ __align__(16) unsigned short lq[64 * 32];
  __shared__ __align__(16) unsigned short lk[64 * 32];
  const int b = blockIdx.x, ks = blockIdx.y;
  const int t = threadIdx.x, lane = t & 63, wid = t >> 6;
  const int sr = lane >> 2, sg = lane & 3;
  const unsigned short* gq = qkv + ((size_t)b * rowsPerBatch + wid * 16 + sr) * ld
                             + ks * 256 + sg * 8;
  const unsigned short* gk = gq + 2048;
  unsigned short* lq0 = &lq[(wid * 16) * 32];
  unsigned short* lk0 = &lk[(wid * 16) * 32];
  const int fm = lane & 15, quad = lane >> 4;
  const unsigned short* aAddr = &lq[(wid * 16 + fm) * 32 + quad * 8];

  facc4 acc[4];
  #pragma unroll
  for (int j = 0; j < 4; j++) acc[j] = 0;

#define STAGE2(k0) do { \
    __builtin_amdgcn_global_load_lds((const __attribute__((address_space(1))) void*)(gq + (k0)), (__attribute__((address_space(3))) void*)(lq0), 16, 0, 0); \
    __builtin_amdgcn_global_load_lds((const __attribute__((address_space(1))) void*)(gk + (k0)), (__attribute__((address_space(3))) void*)(lk0), 16, 0, 0); \
  } while (0)

  STAGE2(0);
  __syncthreads();
  for (int kk = 0;;) {
    const bfrag8 af = *(const bfrag8*)aAddr;
    #pragma unroll
    for (int j = 0; j < 4; j++) {
      const bfrag8 bf = *(const bfrag8*)(&lk[(j * 16 + fm) * 32 + quad * 8]);
      acc[j] = __builtin_amdgcn_mfma_f32_16x16x32_bf16(af, bf, acc[j], 0, 0, 0);
    }
    kk += 32;
    if (kk >= 256) break;
    __syncthreads();
    STAGE2(kk);
    __syncthreads();
  }
#undef STAGE2

  float* sp = Spart + (size_t)(b * 8 + ks) * 4096;
  const int r0 = wid * 16 + quad * 4;
  #pragma unroll
  for (int j = 0; j < 4; j++)
    #pragma unroll
    for (int rr = 0; rr < 4; rr++)
      sp[(r0 + rr) * 64 + j * 16 + fm] = acc[j][rr];
}

// ---------- out-projection partials: Opart[ks][64 b][2048 d] = y16 @ swv16^T (K-chunk) ----------
__global__ __launch_bounds__(256) void outproj(
    const unsigned short* __restrict__ y16, const unsigned short* __restrict__ swv16,
    float* __restrict__ Opart)
{
  __shared__ __align__(16) unsigned short ly[64 * 32];
  __shared__ __align__(16) unsigned short lv[64 * 32];
  const int dt = blockIdx.x, ks = blockIdx.y;     // 32 d-tiles x 8 k-splits
  const int t = threadIdx.x, lane = t & 63, wid = t >> 6;
  const int sr = lane >> 2, sg = lane & 3;
  const unsigned short* gy = y16  + (size_t)(wid * 16 + sr) * 2048 + ks * 256 + sg * 8;
  const unsigned short* gv = swv16 + (size_t)(dt * 64 + wid * 16 + sr) * 2048 + ks * 256 + sg * 8;
  unsigned short* ly0 = &ly[(wid * 16) * 32];
  unsigned short* lv0 = &lv[(wid * 16) * 32];
  const int fm = lane & 15, quad = lane >> 4;
  const unsigned short* aAddr = &ly[(wid * 16 + fm) * 32 + quad * 8];

  facc4 acc[4];
  #pragma unroll
  for (int j = 0; j < 4; j++) acc[j] = 0;

#define STAGE3(k0) do { \
    __builtin_amdgcn_global_load_lds((const __attribute__((address_space(1))) void*)(gy + (k0)), (__attribute__((address_space(3))) void*)(ly0), 16, 0, 0); \
    __builtin_amdgcn_global_load_lds((const __attribute__((address_space(1))) void*)(gv + (k0)), (__attribute__((address_space(3))) void*)(lv0), 16, 0, 0); \
  } while (0)

  STAGE3(0);
  __syncthreads();
  for (int kk = 0;;) {
    const bfrag8 af = *(const bfrag8*)aAddr;
    #pragma unroll
    for (int j = 0; j < 4; j++) {
      const bfrag8 bf = *(const bfrag8*)(&lv[(j * 16 + fm) * 32 + quad * 8]);
      acc[j] = __builtin_amdgcn_mfma_f32_16x16x32_bf16(af, bf, acc[j], 0, 0, 0);
    }
    kk += 32;
    if (kk >= 256) break;
    __syncthreads();
    STAGE3(kk);
    __syncthreads();
  }
#undef STAGE3

  float* op = Opart + (size_t)ks * 131072 + (size_t)dt * 64;
  const int r0 = wid * 16 + quad * 4;   // b row
  #pragma unroll
  for (int j = 0; j < 4; j++)
    #pragma unroll
    for (int rr = 0; rr < 4; rr++)
      op[(size_t)(r0 + rr) * 2048 + j * 16 + fm] = acc[j][rr];
}

// ---------- out[b][d] = sum_ks Opart + sumc2[b]*sbv[d] ----------
__global__ __launch_bounds__(256) void outfin(const float* __restrict__ Opart,
                                              const float* __restrict__ c2buf,
                                              const float* __restrict__ sbv,
                                              float* __restrict__ out){
  const int i = blockIdx.x * 256 + threadIdx.x;   // [0, 131072)
  const int b = i >> 11, d = i & 2047;
  float s = 0.f;
  #pragma unroll
  for (int ks = 0; ks < 8; ks++) s += Opart[(size_t)ks * 131072 + i];
  out[i] = s + c2buf[(size_t)b * 64 + 63] * sbv[d];
}

// ---------- NSA finisher: reduce partials + band softmax column-sums ----------
__global__ __launch_bounds__(512) void nsa_fin(const float* __restrict__ Spart,
                                               float* __restrict__ cbuf){
  __shared__ float Ss[64][65];
  const int b = blockIdx.x, t = threadIdx.x;
  const float* sp = Spart + (size_t)b * 8 * 4096;
  for (int idx = t; idx < 4096; idx += 512) {
    float s = 0.f;
    #pragma unroll
    for (int ks = 0; ks < 8; ks++) s += sp[ks * 4096 + idx];
    Ss[idx >> 6][idx & 63] = s * SCALE_;
  }
  __syncthreads();
  if (t < W_ * 8) {
    const int wi = t >> 3, jp = t & 7;
    float csum = 0.f;
    for (int ip = 0; ip < 8; ip++) {
      const float* row = &Ss[wi + ip][wi];
      float mx = row[0];
      #pragma unroll
      for (int q = 1; q < 8; q++) mx = fmaxf(mx, row[q]);
      float s = 0.f, ej = 0.f;
      #pragma unroll
      for (int q = 0; q < 8; q++) { float e = __expf(row[q] - mx); s += e; if (q == jp) ej = e; }
      csum += ej / s;
    }
    cbuf[((size_t)b * W_ + wi) * 8 + jp] = csum;
  }
}

// ---------- SA2 finisher: reduce partials + softmax column-sums c2[b][j], sumc at slot 63 ----------
__global__ __launch_bounds__(512) void sa2_c2(const float* __restrict__ Spart,
                                              float* __restrict__ c2buf){
  __shared__ float Ss[64][65];
  __shared__ float rowm[64], rowsum[64], c2s[64];
  const int b = blockIdx.x, t = threadIdx.x;
  const float* sp = Spart + (size_t)b * 8 * 4096;
  for (int idx = t; idx < 4096; idx += 512) {
    float s = 0.f;
    #pragma unroll
    for (int ks = 0; ks < 8; ks++) s += sp[ks * 4096 + idx];
    Ss[idx >> 6][idx & 63] = s * SCALE_;
  }
  __syncthreads();
  if (t < W_) {
    float mx = -1e30f;
    for (int j = 0; j < W_; j++) mx = fmaxf(mx, Ss[t][j]);
    float s = 0.f;
    for (int j = 0; j < W_; j++) s += __expf(Ss[t][j] - mx);
    rowm[t] = mx; rowsum[t] = 1.f / s;
  }
  __syncthreads();
  if (t < W_) {
    float cs = 0.f;
    for (int i = 0; i < W_; i++) cs += __expf(Ss[i][t] - rowm[i]) * rowsum[i];
    c2s[t] = cs;
    c2buf[(size_t)b * 64 + t] = cs;
  }
  __syncthreads();
  if (t == 0) {
    float s = 0.f;
    for (int j = 0; j < W_; j++) s += c2s[j];
    c2buf[(size_t)b * 64 + 63] = s;
  }
}

// ---------- y16[b][d] = bf16( sum_j c2[b][j] * hn[b*57+j][d] ) ----------
__global__ __launch_bounds__(256) void ycomb(const unsigned short* __restrict__ hn,
                                             const float* __restrict__ c2buf,
                                             unsigned short* __restrict__ y16){
  const int b = blockIdx.y;
  const int d = blockIdx.x * 256 + threadIdx.x;
  __shared__ float c2[W_];
  if (threadIdx.x < W_) c2[threadIdx.x] = c2buf[(size_t)b * 64 + threadIdx.x];
  __syncthreads();
  const unsigned short* hrow = hn + (size_t)b * W_ * 2048 + d;
  float a = 0.f;
  for (int j = 0; j < W_; j++) a += c2[j] * bf2f(hrow[(size_t)j * 2048]);
  y16[(size_t)b * 2048 + d] = f2bf(a);
}

// ---------- fused h + LayerNorm: hn[b*57+w][:] = LN(ds-proj + nsa), bf16 ----------
// grid 520 (1D): flat<512 -> wg=flat>>6 (8 w-rows, tail rows padded), b=flat&63
//                flat>=512 -> zero pad rows [3648,3712)
// ALL acc indices are compile-time constants (runtime indexing spills to scratch
// -> 1.5 GB of memory traffic, measured R5).
typedef __attribute__((ext_vector_type(8))) unsigned short us8;
__global__ __launch_bounds__(256) void hln_kernel(
    const unsigned short* __restrict__ fc16, const float* __restrict__ dsw,
    const float* __restrict__ dsb, const unsigned short* __restrict__ qkv,
    const float* __restrict__ cbuf, const float* __restrict__ g,
    const float* __restrict__ be, unsigned short* __restrict__ hn)
{
  const int flat = blockIdx.x;
  const int t = threadIdx.x;
  if (flat >= 512) {
    const int p = flat - 512;                      // 8 blocks, 8 rows each
    unsigned short* orow = hn + (size_t)(3648 + p * 8) * 2048;
    for (int i = t; i < 8 * 2048; i += 256) orow[i] = 0;
    return;
  }
  const int wg = flat >> 6, b = flat & 63;         // flat&7 = b&7 -> batch pinned to XCD
  const int w0 = wg * 8;
  __shared__ float dswl[8 * 64];
  __shared__ float cl[8 * 8];
  __shared__ float dsbl[8];
  __shared__ float red[4][8][2];
  for (int i = t; i < 8 * 64; i += 256) {
    const int w = w0 + (i >> 6);
    dswl[i] = (w < W_) ? dsw[w * 64 + (i & 63)] : 0.f;
  }
  if (t < 64) {
    const int w = w0 + (t >> 3);
    cl[t] = (w < W_) ? cbuf[((size_t)b * W_ + w) * 8 + (t & 7)] : 0.f;
  }
  if (t < 8) dsbl[t] = (w0 + t < W_) ? dsb[w0 + t] : 0.f;
  __syncthreads();

  const int d0 = t * 8;                            // this thread's 8 contiguous d
  float acc[8][8];
  #pragma unroll
  for (int w = 0; w < 8; w++)
    #pragma unroll
    for (int p = 0; p < 8; p++) acc[w][p] = 0.f;

  // ds-GEMM: acc[w][p] += fc[b][n][d0+p] * dsw[w0+w][n]
  for (int n = 0; n < 64; n++) {
    const us8 fv8 = *(const us8*)(fc16 + ((size_t)b * 64 + n) * 2048 + d0);
    float fv[8];
    #pragma unroll
    for (int p = 0; p < 8; p++) fv[p] = bf2f(fv8[p]);
    #pragma unroll
    for (int w = 0; w < 8; w++) {
      const float dv = dswl[w * 64 + n];
      #pragma unroll
      for (int p = 0; p < 8; p++) acc[w][p] += fv[p] * dv;
    }
  }
  // nsa combine: v rows w0..w0+14 (row clamped; tail garbage hits cl==0)
  #pragma unroll
  for (int r = 0; r < 15; r++) {
    const int row = (w0 + r < 64) ? (w0 + r) : 63;
    const us8 vv8 = *(const us8*)(qkv + ((size_t)b * 64 + row) * QKVLD + 4096 + d0);
    float vv[8];
    #pragma unroll
    for (int p = 0; p < 8; p++) vv[p] = bf2f(vv8[p]);
    #pragma unroll
    for (int j = 0; j < 8; j++) {
      if (r - j >= 0 && r - j < 8) {
        const float cv = cl[(r - j) * 8 + j];
        #pragma unroll
        for (int p = 0; p < 8; p++) acc[r - j][p] += cv * vv[p];
      }
    }
  }
  // add bias, per-row partial sums
  float s1[8], s2v[8];
  #pragma unroll
  for (int w = 0; w < 8; w++) {
    const float bb = dsbl[w];
    float a1 = 0.f, a2 = 0.f;
    #pragma unroll
    for (int p = 0; p < 8; p++) {
      acc[w][p] += bb;
      a1 += acc[w][p];
      a2 += acc[w][p] * acc[w][p];
    }
    s1[w] = a1; s2v[w] = a2;
  }
  // wave reduce then LDS combine (single sync)
  const int wv = t >> 6, lane = t & 63;
  #pragma unroll
  for (int w = 0; w < 8; w++) {
    #pragma unroll
    for (int off = 32; off >= 1; off >>= 1) {
      s1[w]  += __shfl_down(s1[w], off);
      s2v[w] += __shfl_down(s2v[w], off);
    }
    if (lane == 0) { red[wv][w][0] = s1[w]; red[wv][w][1] = s2v[w]; }
  }
  __syncthreads();
  const float4 g0 = *(const float4*)(g + d0),  g1 = *(const float4*)(g + d0 + 4);
  const float4 e0 = *(const float4*)(be + d0), e1 = *(const float4*)(be + d0 + 4);
  const float gp[8] = {g0.x,g0.y,g0.z,g0.w,g1.x,g1.y,g1.z,g1.w};
  const float ep[8] = {e0.x,e0.y,e0.z,e0.w,e1.x,e1.y,e1.z,e1.w};
  #pragma unroll
  for (int w = 0; w < 8; w++) {
    if (w0 + w >= W_) break;
    const float st  = red[0][w][0] + red[1][w][0] + red[2][w][0] + red[3][w][0];
    const float st2 = red[0][w][1] + red[1][w][1] + red[2][w][1] + red[3][w][1];
    const float mu  = st * (1.f / 2048.f);
    const float var = st2 * (1.f / 2048.f) - mu * mu;
    const float rstd = rsqrtf(var + 1e-5f);
    us8 o;
    #pragma unroll
    for (int p = 0; p < 8; p++)
      o[p] = f2bf((acc[w][p] - mu) * rstd * gp[p] + ep[p]);
    *(us8*)(hn + (size_t)(b * W_ + w0 + w) * 2048 + d0) = o;
  }
}

// ---------- launch ----------
extern "C" void kernel_launch(void* const* d_in, const int* in_sizes, int n_in,
                              void* d_out, int out_size, void* d_ws, size_t ws_size,
                              hipStream_t stream)
{
  const float* fc  = (const float*)d_in[0];
  const float* nwq = (const float*)d_in[1];
  const float* nbq = (const float*)d_in[2];
  const float* nwk = (const float*)d_in[3];
  const float* nbk = (const float*)d_in[4];
  const float* nwv = (const float*)d_in[5];
  const float* nbv = (const float*)d_in[6];
  const float* dsw = (const float*)d_in[7];
  const float* dsb = (const float*)d_in[8];
  const float* lng = (const float*)d_in[9];
  const float* lnb = (const float*)d_in[10];
  const float* swq = (const float*)d_in[11];
  const float* sbq = (const float*)d_in[12];
  const float* swk = (const float*)d_in[13];
  const float* sbk = (const float*)d_in[14];
  const float* swv = (const float*)d_in[15];
  const float* sbv = (const float*)d_in[16];
  (void)sbk;

  char* ws = (char*)d_ws;
  unsigned short* fc16  = (unsigned short*)(ws + 0);          // 16.8 MB
  unsigned short* wcat  = (unsigned short*)(ws + 16777216);   // 25.2 MB (nsa weights; dead after gemm1)
  float* Spart          = (float*)(ws + 16777216);            // 8.4 MB — aliases wcat head
  unsigned short* wcat2 = (unsigned short*)(ws + 25165824);   // 16.8 MB ([swq;swk]; dead after gemm2)
  float* bcat1          = (float*)(ws + 41943040);            // 24 KB
  float* bcat2          = (float*)(ws + 41967616);            // 16 KB used
  unsigned short* qkv   = (unsigned short*)(ws + 41992192);   // 50.3 MB (phase2: q2|k2 30.4 MB)
  float* cbuf           = (float*)(ws + 92323840);            // 117 KB (reused: c2buf)
  float* c2buf          = (float*)(ws + 92323840);            // aliases cbuf (disjoint lifetime)
  unsigned short* swv16 = (unsigned short*)(ws + 92440576);   // 8.4 MB
  unsigned short* y16   = (unsigned short*)(ws + 100829184);  // 256 KB
  float* Opart          = (float*)(ws + 101091328);           // 4 MB
  unsigned short* hn    = (unsigned short*)(ws + 122324992);  // 15.2 MB   (total ~137.5 MB)

  // fused casts + bias concats (exact grid: 5249024 / 256 = 20504)
  castA<<<20504, 256, 0, stream>>>(fc, nwq, nwk, nwv, nbq, nbk, nbv, sbq, sbk,
                                   fc16, wcat, bcat1, bcat2);

  // qkv = fc16 @ [wq;wk;wv]^T + bias   (M=4096, N=6144, K=2048), 48 col-tiles, 6/XCD
  gemm_bt<<<32 * 48, 256, 0, stream>>>(fc16, wcat, bcat1, qkv, 6144, 2048, 6);

  // NSA band scores via MFMA, K-split x8 (Spart overwrites nsa weights — gemm1 done)
  scores_kernel<<<dim3(64, 8), 256, 0, stream>>>(qkv, 64, QKVLD, Spart);
  nsa_fin<<<64, 512, 0, stream>>>(Spart, cbuf);

  // fused h + LayerNorm -> hn (bf16; pad rows zeroed by blocks 512..519)
  hln_kernel<<<520, 256, 0, stream>>>(fc16, dsw, dsb, qkv, cbuf, lng, lnb, hn);

  // sa weights: swq,swk -> wcat2, swv -> swv16
  castB3<<<12288, 256, 0, stream>>>(swq, swk, swv, wcat2, swv16);

  // q2|k2 = hn @ [swq;swk]^T + bias  (M=3712 padded, N=4096, K=2048), 32 col-tiles, 4/XCD
  gemm_bt<<<29 * 32, 256, 0, stream>>>(hn, wcat2, bcat2, qkv, 4096, 2048, 4);

  // SA2 scores via MFMA (rows b*57..b*57+63; max 3654 < 3712, in-bounds)
  scores_kernel<<<dim3(64, 8), 256, 0, stream>>>(qkv, W_, QKLD, Spart);
  sa2_c2<<<64, 512, 0, stream>>>(Spart, c2buf);

  // y16 = bf16(c2^T · hn); out = y16 @ swv16^T (MFMA, K-split x8) + sumc*sbv
  ycomb<<<dim3(8, 64), 256, 0, stream>>>(hn, c2buf, y16);
  outproj<<<dim3(32, 8), 256, 0, stream>>>(y16, swv16, Opart);
  outfin<<<512, 256, 0, stream>>>(Opart, c2buf, sbv, (float*)d_out);

  (void)in_sizes; (void)n_in; (void)out_size; (void)ws_size;
}